// Round 6
// baseline (31.074 us; speedup 1.0000x reference)
//
#include <hip/hip_runtime.h>

constexpr int TPB = 256;
constexpr int ROWS = 2;
constexpr int RPB = TPB * ROWS;   // 512 rows per block

typedef float fvec4 __attribute__((ext_vector_type(4)));

__global__ __launch_bounds__(TPB) void attctl_kernel(
    const float* __restrict__ rs,        // [n,13] root_state
    const float4* __restrict__ ct,       // [n,4]  control_target
    const float* __restrict__ mass_p,    // [1]
    const float* __restrict__ g_p,       // [1]
    const float* __restrict__ mixer,     // [4,4] row-major
    const float* __restrict__ max_thr,   // [4]
    const float* __restrict__ g_att,     // [3]
    const float* __restrict__ g_rate,    // [3]
    float4* __restrict__ out,            // [n,4]
    int n)
{
    const int t = threadIdx.x;
    const long long bstart = (long long)blockIdx.x * RPB;
    const long long row0 = bstart + t;
    const long long row1 = bstart + TPB + t;

    // Issue all independent loads up front (deep MLP, no LDS, no barrier).
    float4 qv0, av0, c0, qv1, av1, c1;
    qv0 = av0 = c0 = qv1 = av1 = c1 = make_float4(0.f, 0.f, 0.f, 0.f);
    if (row0 < n) {
        const float* p0 = rs + row0 * 13;
        qv0 = *reinterpret_cast<const float4*>(p0 + 3);   // w,x,y,z
        av0 = *reinterpret_cast<const float4*>(p0 + 9);   // _,wx,wy,wz
        c0  = ct[row0];
    }
    if (row1 < n) {
        const float* p1 = rs + row1 * 13;
        qv1 = *reinterpret_cast<const float4*>(p1 + 3);
        av1 = *reinterpret_cast<const float4*>(p1 + 9);
        c1  = ct[row1];
    }

    // Wave-uniform constants (scalar loads).
    const float ga0 = g_att[0], ga1 = g_att[1];
    const float gr0 = g_rate[0], gr1 = g_rate[1], gr2 = g_rate[2];
    const float mg = mass_p[0] * g_p[0];
    const float inv0 = 2.0f / max_thr[0];
    const float inv1 = 2.0f / max_thr[1];
    const float inv2 = 2.0f / max_thr[2];
    const float inv3 = 2.0f / max_thr[3];
    const float m00 = mixer[0],  m01 = mixer[1],  m02c = mixer[2],  m03 = mixer[3];
    const float m10 = mixer[4],  m11 = mixer[5],  m12c = mixer[6],  m13 = mixer[7];
    const float m20 = mixer[8],  m21 = mixer[9],  m22c = mixer[10], m23 = mixer[11];
    const float m30 = mixer[12], m31 = mixer[13], m32c = mixer[14], m33 = mixer[15];

    #pragma unroll
    for (int r = 0; r < ROWS; ++r) {
        const long long row = (r == 0) ? row0 : row1;
        if (row >= n) continue;
        const float4 qv = (r == 0) ? qv0 : qv1;
        const float4 av = (r == 0) ? av0 : av1;
        const float4 c  = (r == 0) ? c0  : c1;

        const float w = qv.x, x = qv.y, y = qv.z, z = qv.w;
        const float avx = av.y, avy = av.z, avz = av.w;
        const float roll = c.x, pitch = c.y, yawr = c.z, thr_in = c.w;

        const float sr = __sinf(roll),  cr = __cosf(roll);
        const float sp = __sinf(pitch), cp = __cosf(pitch);
        const float sy = __sinf(yawr),  cy = __cosf(yawr);

        // quaternion -> R (pre-normalized)
        const float xx = x*x, yy = y*y, zz = z*z;
        const float xy = x*y, xz = x*z, yz = y*z;
        const float wx = w*x, wy = w*y, wz = w*z;
        const float r00 = 1.f - 2.f*(yy+zz), r01 = 2.f*(xy-wz),       r02 = 2.f*(xz+wy);
        const float r10 = 2.f*(xy+wz),       r11 = 1.f - 2.f*(xx+zz), r12 = 2.f*(yz-wx);
        const float r20 = 2.f*(xz-wy),       r21 = 2.f*(yz+wx),       r22 = 1.f - 2.f*(xx+yy);

        // R_des = Rz(yawr) * Rx(roll) * Ry(pitch)
        const float d00 = cy*cp - sy*sr*sp;
        const float d01 = -sy*cr;
        const float d02 = cy*sp + sy*sr*cp;
        const float d10 = sy*cp + cy*sr*sp;
        const float d11 = cy*cr;
        const float d12 = sy*sp - cy*sr*cp;
        const float d20 = -cr*sp;
        const float d21 = sr;
        const float d22 = cr*cp;

        // M = R_des^T @ R ; only 5 entries needed.
        const float M02 = d00*r02 + d10*r12 + d20*r22;
        const float M20 = d02*r00 + d12*r10 + d22*r20;
        const float M12 = d01*r02 + d11*r12 + d21*r22;
        const float M21 = d02*r01 + d12*r11 + d22*r21;
        const float M22 = d02*r02 + d12*r12 + d22*r22;

        const float ae0 = 0.5f*(M21 - M12);
        const float ae1 = 0.5f*(M02 - M20);
        // ae2 == 0; cross(v,v) == 0 exactly -> dropped

        const float re0 = avx - M02*yawr;
        const float re1 = avy - M12*yawr;
        const float re2 = avz - M22*yawr;

        const float a0 = -ae0*ga0 - re0*gr0;
        const float a1 = -ae1*ga1 - re1*gr1;
        const float a2 = -re2*gr2;
        const float th = thr_in * mg;

        fvec4 o;
        o.x = (a0*m00 + a1*m01 + a2*m02c + th*m03) * inv0 - 1.f;
        o.y = (a0*m10 + a1*m11 + a2*m12c + th*m13) * inv1 - 1.f;
        o.z = (a0*m20 + a1*m21 + a2*m22c + th*m23) * inv2 - 1.f;
        o.w = (a0*m30 + a1*m31 + a2*m32c + th*m33) * inv3 - 1.f;
        // Output is never re-read: nontemporal store avoids cache pollution.
        __builtin_nontemporal_store(o, reinterpret_cast<fvec4*>(&out[row]));
    }
}

extern "C" void kernel_launch(void* const* d_in, const int* in_sizes, int n_in,
                              void* d_out, int out_size, void* d_ws, size_t ws_size,
                              hipStream_t stream) {
    const float*  rs    = (const float*)d_in[0];
    const float4* ctrl  = (const float4*)d_in[1];
    const float*  mass  = (const float*)d_in[2];
    const float*  g     = (const float*)d_in[3];
    const float*  mixer = (const float*)d_in[4];
    const float*  mt    = (const float*)d_in[5];
    const float*  ga    = (const float*)d_in[6];
    const float*  gr    = (const float*)d_in[7];
    float4* out = (float4*)d_out;

    const int n = in_sizes[0] / 13;
    const int blocks = (n + RPB - 1) / RPB;
    hipLaunchKernelGGL(attctl_kernel, dim3(blocks), dim3(TPB), 0, stream,
                       rs, ctrl, mass, g, mixer, mt, ga, gr, out, n);
}

// Round 7
// 29.799 us; speedup vs baseline: 1.0428x; 1.0428x over previous
//
#include <hip/hip_runtime.h>

constexpr int TPB = 256;

typedef float fvec4 __attribute__((ext_vector_type(4)));

__global__ __launch_bounds__(TPB) void attctl_kernel(
    const float* __restrict__ rs,        // [n,13] root_state
    const float4* __restrict__ ct,       // [n,4]  control_target
    const float* __restrict__ mass_p,    // [1]
    const float* __restrict__ g_p,       // [1]
    const float* __restrict__ mixer,     // [4,4] row-major
    const float* __restrict__ max_thr,   // [4]
    const float* __restrict__ g_att,     // [3]
    const float* __restrict__ g_rate,    // [3]
    float4* __restrict__ out,            // [n,4]
    int n)
{
    const long long row = (long long)blockIdx.x * TPB + threadIdx.x;
    if (row >= n) return;

    const float* rowp = rs + row * 13;
    // Dword-aligned vector loads of exactly the needed fields.
    // floats 3..6: quat (w,x,y,z); floats 9..12: (pad, wx, wy, wz)
    const float4 qv = *reinterpret_cast<const float4*>(rowp + 3);
    const float4 av = *reinterpret_cast<const float4*>(rowp + 9);
    const float4 c  = ct[row];

    const float w = qv.x, x = qv.y, y = qv.z, z = qv.w;
    const float avx = av.y, avy = av.z, avz = av.w;
    const float roll = c.x, pitch = c.y, yawr = c.z, thr_in = c.w;

    const float sr = __sinf(roll),  cr = __cosf(roll);
    const float sp = __sinf(pitch), cp = __cosf(pitch);
    const float sy = __sinf(yawr),  cy = __cosf(yawr);

    // quaternion -> R (pre-normalized)
    const float xx = x*x, yy = y*y, zz = z*z;
    const float xy = x*y, xz = x*z, yz = y*z;
    const float wx = w*x, wy = w*y, wz = w*z;
    const float r00 = 1.f - 2.f*(yy+zz), r01 = 2.f*(xy-wz),       r02 = 2.f*(xz+wy);
    const float r10 = 2.f*(xy+wz),       r11 = 1.f - 2.f*(xx+zz), r12 = 2.f*(yz-wx);
    const float r20 = 2.f*(xz-wy),       r21 = 2.f*(yz+wx),       r22 = 1.f - 2.f*(xx+yy);

    // R_des = Rz(yawr) * Rx(roll) * Ry(pitch)
    const float d00 = cy*cp - sy*sr*sp;
    const float d01 = -sy*cr;
    const float d02 = cy*sp + sy*sr*cp;
    const float d10 = sy*cp + cy*sr*sp;
    const float d11 = cy*cr;
    const float d12 = sy*sp - cy*sr*cp;
    const float d20 = -cr*sp;
    const float d21 = sr;
    const float d22 = cr*cp;

    // M = R_des^T @ R ; only 5 entries needed.
    const float M02 = d00*r02 + d10*r12 + d20*r22;
    const float M20 = d02*r00 + d12*r10 + d22*r20;
    const float M12 = d01*r02 + d11*r12 + d21*r22;
    const float M21 = d02*r01 + d12*r11 + d22*r21;
    const float M22 = d02*r02 + d12*r12 + d22*r22;

    const float ae0 = 0.5f*(M21 - M12);
    const float ae1 = 0.5f*(M02 - M20);
    // ae2 == 0; cross(ang_vel, ang_vel) == 0 exactly -> dropped

    const float re0 = avx - M02*yawr;
    const float re1 = avy - M12*yawr;
    const float re2 = avz - M22*yawr;

    const float ga0 = g_att[0], ga1 = g_att[1];
    const float gr0 = g_rate[0], gr1 = g_rate[1], gr2 = g_rate[2];

    const float a0 = -ae0*ga0 - re0*gr0;
    const float a1 = -ae1*ga1 - re1*gr1;
    const float a2 = -re2*gr2;
    const float th = thr_in * mass_p[0] * g_p[0];

    const float inv0 = 2.0f / max_thr[0];
    const float inv1 = 2.0f / max_thr[1];
    const float inv2 = 2.0f / max_thr[2];
    const float inv3 = 2.0f / max_thr[3];

    fvec4 o;
    o.x = (a0*mixer[0]  + a1*mixer[1]  + a2*mixer[2]  + th*mixer[3])  * inv0 - 1.f;
    o.y = (a0*mixer[4]  + a1*mixer[5]  + a2*mixer[6]  + th*mixer[7])  * inv1 - 1.f;
    o.z = (a0*mixer[8]  + a1*mixer[9]  + a2*mixer[10] + th*mixer[11]) * inv2 - 1.f;
    o.w = (a0*mixer[12] + a1*mixer[13] + a2*mixer[14] + th*mixer[15]) * inv3 - 1.f;
    // Output is never re-read: nontemporal store avoids L2/L3 write allocation,
    // leaving more cache for the read stream.
    __builtin_nontemporal_store(o, reinterpret_cast<fvec4*>(&out[row]));
}

extern "C" void kernel_launch(void* const* d_in, const int* in_sizes, int n_in,
                              void* d_out, int out_size, void* d_ws, size_t ws_size,
                              hipStream_t stream) {
    const float*  rs    = (const float*)d_in[0];
    const float4* ctrl  = (const float4*)d_in[1];
    const float*  mass  = (const float*)d_in[2];
    const float*  g     = (const float*)d_in[3];
    const float*  mixer = (const float*)d_in[4];
    const float*  mt    = (const float*)d_in[5];
    const float*  ga    = (const float*)d_in[6];
    const float*  gr    = (const float*)d_in[7];
    float4* out = (float4*)d_out;

    const int n = in_sizes[0] / 13;
    const int blocks = (n + TPB - 1) / TPB;
    hipLaunchKernelGGL(attctl_kernel, dim3(blocks), dim3(TPB), 0, stream,
                       rs, ctrl, mass, g, mixer, mt, ga, gr, out, n);
}